// Round 5
// baseline (320.578 us; speedup 1.0000x reference)
//
#include <hip/hip_runtime.h>
#include <hip/hip_fp16.h>
#include <hip/hip_cooperative_groups.h>

namespace cg = cooperative_groups;

// Problem geometry: inputs (B=2, D=64, H=64, W=64, C=32) fp32, C innermost.
// Pass1: Sobel (VALID) -> mag = sqrt(gx^2+gy^2+gz^2) at 62^3 per (b,c)
// Pass2: Sobel on mag -> out = sqrt(gx^2+gy^2) + gz^2 at 60^3
// Result: mean(|out_pred - out_hr|) over 2*32*60^3 = 13,824,000 elems.
//
// R9: single cooperative dispatch. Evidence R4-R8: sum(kernel dur) ~170-205us
// but wall 245-280us -> 55-85us of inter-dispatch dead time, the largest
// single cost. Also: three different in-flight structures (direct loads,
// reg-prefetch, LDS-DMA) all converge to ~9 GB/s/CU, so in-kernel structure
// changes are currently second-order. This round changes exactly ONE thing:
// dispatch count. One hipLaunchCooperativeKernel, grid 512 (2 blocks/CU
// guaranteed by __launch_bounds__(256,2)): phase1 = 1984 P1 units (R7 body
// verbatim, fastest measured), grid.sync(), phase2 = 1440 P2 units (R7 body),
// fused finalize. 4 mag buffers (61MB ws). Fallback: R7 multi-dispatch chain.

constexpr int BDIM = 256;
constexpr int NB   = 512;          // fused grid: 2 blocks/CU on 256 CUs
constexpr size_t IN_B = 8388608;   // floats per batch
constexpr int IN_D = 131072;       // floats per z-plane
constexpr int IN_H = 2048;         // floats per y-row
constexpr int M = 62;              // mag spatial dim
constexpr int F = 60;              // final spatial dim
constexpr int C = 32;
constexpr int MROW = M * C;                      // 1984 halves per mag row
constexpr size_t MAGSZ = (size_t)M * M * MROW;   // halves per mag buffer
constexpr size_t PLANE = (size_t)M * MROW;       // halves per mag z-plane

__device__ __forceinline__ float4 ld4(const float* p) {
    return *reinterpret_cast<const float4*>(p);
}
__device__ __forceinline__ float2 ldh2(const __half* p) {
    return __half22float2(*reinterpret_cast<const __half2*>(p));
}
__device__ __forceinline__ float4 sm3(float4 a, float4 b, float4 c) {
    return make_float4(a.x + 2.f * b.x + c.x, a.y + 2.f * b.y + c.y,
                       a.z + 2.f * b.z + c.z, a.w + 2.f * b.w + c.w);
}
__device__ __forceinline__ float4 df2(float4 a, float4 c) {
    return make_float4(c.x - a.x, c.y - a.y, c.z - a.z, c.w - a.w);
}

// ===================== Pass 1 unit (R7 body, proven) =====================
struct P1W { float4 A[2], B[2], C[2]; };

__device__ __forceinline__ void p1_plane(const float* __restrict__ col, size_t zoff,
                                         P1W& W)
{
    float4 S[4], D[4];
#pragma unroll
    for (int r = 0; r < 4; ++r) {
        const float* p = col + zoff + (size_t)r * IN_H;
        float4 a = ld4(p), b = ld4(p + C), c = ld4(p + 2 * C);
        S[r] = sm3(a, b, c);
        D[r] = df2(a, c);
    }
#pragma unroll
    for (int k = 0; k < 2; ++k) {
        W.A[k] = sm3(S[k], S[k+1], S[k+2]);
        W.B[k] = df2(S[k], S[k+2]);
        W.C[k] = sm3(D[k], D[k+1], D[k+2]);
    }
}

__device__ __forceinline__ void p1_emit(const P1W& W0, const P1W& W1, const P1W& W2,
                                        __half* __restrict__ mag, size_t cb,
                                        int z, int y0, bool wr)
{
    if (!wr) return;
#pragma unroll
    for (int k = 0; k < 2; ++k) {
        float4 gx = df2(W0.A[k], W2.A[k]);
        float4 gy = sm3(W0.B[k], W1.B[k], W2.B[k]);
        float4 gz = sm3(W0.C[k], W1.C[k], W2.C[k]);
        float m0 = sqrtf(gx.x * gx.x + gy.x * gy.x + gz.x * gz.x);
        float m1 = sqrtf(gx.y * gx.y + gy.y * gy.y + gz.y * gz.y);
        float m2 = sqrtf(gx.z * gx.z + gy.z * gy.z + gz.z * gz.z);
        float m3 = sqrtf(gx.w * gx.w + gy.w * gy.w + gz.w * gz.w);
        union { __half2 h[2]; float2 f; } u;
        u.h[0] = __floats2half2_rn(m0, m1);
        u.h[1] = __floats2half2_rn(m2, m3);
        *reinterpret_cast<float2*>(mag + ((size_t)z * M + (y0 + k)) * MROW + cb)
            = u.f;
    }
}

// bx in [0,62): xt = bx&1, yt = bx>>1. zc in [0,8).
__device__ __forceinline__ void p1_unit(const float* __restrict__ in,
                                        __half* __restrict__ mag,
                                        int b, int bx, int zc, int tid)
{
    const int xt = bx & 1, yt = bx >> 1;
    const int c4 = (tid & 7) << 2;           // channel base 0..28
    const int xl = tid >> 3;                 // 0..31
    const int x  = xt * 30 + xl;             // output x in [0,62)
    const bool wr = (xt == 0) || (xl >= 2);  // tile1 skips duplicated x=30,31
    const int y0 = yt * 2;
    const int z0 = zc * 8;
    const int zn = min(8, M - z0);           // 8, last chunk 6

    const float* col = in + (size_t)b * IN_B + (size_t)y0 * IN_H
                          + (size_t)x * C + c4;
    const size_t cb = (size_t)x * C + c4;

    P1W W0, W1, W2;
    p1_plane(col, (size_t)(z0 + 0) * IN_D, W0);
    p1_plane(col, (size_t)(z0 + 1) * IN_D, W1);
    int z = 0;
    while (true) {
        p1_plane(col, (size_t)(z0 + z + 2) * IN_D, W2);
        p1_emit(W0, W1, W2, mag, cb, z0 + z, y0, wr);
        if (++z >= zn) break;
        p1_plane(col, (size_t)(z0 + z + 2) * IN_D, W0);
        p1_emit(W1, W2, W0, mag, cb, z0 + z, y0, wr);
        if (++z >= zn) break;
        p1_plane(col, (size_t)(z0 + z + 2) * IN_D, W1);
        p1_emit(W2, W0, W1, mag, cb, z0 + z, y0, wr);
        if (++z >= zn) break;
    }
}

// ===================== Pass 2 unit (R7 body, proven) =====================
struct P2W { float2 A[2], B[2], C[2]; };

__device__ __forceinline__ void p2_plane(const __half* __restrict__ col, size_t zoff,
                                         P2W& W)
{
    float2 SX[4], DX[4];
#pragma unroll
    for (int j = 0; j < 4; ++j) {
        const __half* p = col + zoff + (size_t)j * MROW;
        float2 a = ldh2(p), b = ldh2(p + C), c = ldh2(p + 2 * C);
        SX[j] = make_float2(a.x + 2.f * b.x + c.x, a.y + 2.f * b.y + c.y);
        DX[j] = make_float2(c.x - a.x, c.y - a.y);
    }
#pragma unroll
    for (int k = 0; k < 2; ++k) {
        W.A[k] = make_float2(SX[k].x + 2.f * SX[k+1].x + SX[k+2].x,
                             SX[k].y + 2.f * SX[k+1].y + SX[k+2].y);
        W.B[k] = make_float2(SX[k+2].x - SX[k].x, SX[k+2].y - SX[k].y);
        W.C[k] = make_float2(DX[k].x + 2.f * DX[k+1].x + DX[k+2].x,
                             DX[k].y + 2.f * DX[k+1].y + DX[k+2].y);
    }
}

__device__ __forceinline__ void p2_emit(const P2W& P0, const P2W& P1, const P2W& P2,
                                        const P2W& H0, const P2W& H1, const P2W& H2,
                                        float& acc)
{
#pragma unroll
    for (int k = 0; k < 2; ++k) {
        float gxPx = P2.A[k].x - P0.A[k].x;
        float gxPy = P2.A[k].y - P0.A[k].y;
        float gyPx = P0.B[k].x + 2.f * P1.B[k].x + P2.B[k].x;
        float gyPy = P0.B[k].y + 2.f * P1.B[k].y + P2.B[k].y;
        float gzPx = P0.C[k].x + 2.f * P1.C[k].x + P2.C[k].x;
        float gzPy = P0.C[k].y + 2.f * P1.C[k].y + P2.C[k].y;
        float gxHx = H2.A[k].x - H0.A[k].x;
        float gxHy = H2.A[k].y - H0.A[k].y;
        float gyHx = H0.B[k].x + 2.f * H1.B[k].x + H2.B[k].x;
        float gyHy = H0.B[k].y + 2.f * H1.B[k].y + H2.B[k].y;
        float gzHx = H0.C[k].x + 2.f * H1.C[k].x + H2.C[k].x;
        float gzHy = H0.C[k].y + 2.f * H1.C[k].y + H2.C[k].y;
        float oPx = sqrtf(gxPx * gxPx + gyPx * gyPx) + gzPx * gzPx;
        float oPy = sqrtf(gxPy * gxPy + gyPy * gyPy) + gzPy * gzPy;
        float oHx = sqrtf(gxHx * gxHx + gyHx * gyHx) + gzHx * gzHx;
        float oHy = sqrtf(gxHy * gxHy + gyHy * gyHy) + gzHy * gzHy;
        acc += fabsf(oPx - oHx) + fabsf(oPy - oHy);
    }
}

// bx in [0,120): xt = bx&3, yt = bx>>2. zc in [0,6).
__device__ __forceinline__ void p2_unit(const __half* __restrict__ magP,
                                        const __half* __restrict__ magH,
                                        int bx, int zc, int tid, float& acc)
{
    const int xt = bx & 3, yt = bx >> 2;
    const int y0 = yt * 2;
    const int z0 = zc * 10;
    const int xraw = xt * 16 + (tid >> 4);
    const bool xok = xraw < F;
    const int x = min(xraw, F - 1);
    const int c2 = (tid & 15) << 1;

    const size_t colo = (size_t)y0 * MROW + (size_t)x * C + c2;
    const __half* colP = magP + colo;
    const __half* colH = magH + colo;

    P2W P0, P1, P2, H0, H1, H2;
    p2_plane(colP, (size_t)(z0 + 0) * PLANE, P0);
    p2_plane(colH, (size_t)(z0 + 0) * PLANE, H0);
    p2_plane(colP, (size_t)(z0 + 1) * PLANE, P1);
    p2_plane(colH, (size_t)(z0 + 1) * PLANE, H1);
    int z = 0;
    while (true) {
        p2_plane(colP, (size_t)(z0 + z + 2) * PLANE, P2);
        p2_plane(colH, (size_t)(z0 + z + 2) * PLANE, H2);
        if (xok) p2_emit(P0, P1, P2, H0, H1, H2, acc);
        if (++z >= 10) break;
        p2_plane(colP, (size_t)(z0 + z + 2) * PLANE, P0);
        p2_plane(colH, (size_t)(z0 + z + 2) * PLANE, H0);
        if (xok) p2_emit(P1, P2, P0, H1, H2, H0, acc);
        if (++z >= 10) break;
        p2_plane(colP, (size_t)(z0 + z + 2) * PLANE, P1);
        p2_plane(colH, (size_t)(z0 + z + 2) * PLANE, H1);
        if (xok) p2_emit(P2, P0, P1, H2, H0, H1, acc);
        if (++z >= 10) break;
    }
}

// ============== shared tail: block reduce + last-block finalize ==============
__device__ __forceinline__ void tail_reduce(float acc, float* __restrict__ partial,
                                            size_t pidx, unsigned* __restrict__ counter,
                                            unsigned npart, float* __restrict__ out,
                                            int tid)
{
    for (int o = 32; o > 0; o >>= 1) acc += __shfl_down(acc, o, 64);
    __shared__ float sred[BDIM / 64];
    __shared__ int isLast;
    __shared__ double sd[BDIM / 64];
    const int lane = tid & 63, wv = tid >> 6;
    if (lane == 0) sred[wv] = acc;
    __syncthreads();
    if (tid == 0) {
        float t = 0.f;
#pragma unroll
        for (int i = 0; i < BDIM / 64; ++i) t += sred[i];
        __hip_atomic_store(&partial[pidx], t, __ATOMIC_RELAXED,
                           __HIP_MEMORY_SCOPE_AGENT);
        const unsigned old = __hip_atomic_fetch_add(counter, 1u, __ATOMIC_ACQ_REL,
                                                    __HIP_MEMORY_SCOPE_AGENT);
        isLast = (old == npart - 1u) ? 1 : 0;
    }
    __syncthreads();
    if (isLast) {
        double a = 0.0;
        for (unsigned i = tid; i < npart; i += BDIM)
            a += (double)__hip_atomic_load(&partial[i], __ATOMIC_RELAXED,
                                           __HIP_MEMORY_SCOPE_AGENT);
        for (int o = 32; o > 0; o >>= 1) a += __shfl_down(a, o, 64);
        if (lane == 0) sd[wv] = a;
        __syncthreads();
        if (tid == 0) {
            double t = 0.0;
#pragma unroll
            for (int i = 0; i < BDIM / 64; ++i) t += sd[i];
            out[0] = (float)(t / 13824000.0);
        }
    }
}

// ===================== fused cooperative kernel =====================
// mag layout: magBase + (b*2 + inp)*MAGSZ, inp 0=pred, 1=hr.
__global__ __launch_bounds__(BDIM, 2) void sobel_fused(
    const float* __restrict__ pred, const float* __restrict__ hr,
    __half* __restrict__ magBase, float* __restrict__ partial,
    unsigned* __restrict__ counter, float* __restrict__ out)
{
    const int tid = threadIdx.x;
    if (blockIdx.x == 0 && tid == 0)
        __hip_atomic_store(counter, 0u, __ATOMIC_RELAXED,
                           __HIP_MEMORY_SCOPE_AGENT);

    // Phase 1: 1984 units = 62 bx * 8 zc * 2 inp * 2 b
    for (int u = blockIdx.x; u < 1984; u += NB) {
        const int bx = u % 62;
        int r = u / 62;
        const int zc  = r & 7;  r >>= 3;
        const int inp = r & 1;
        const int b   = r >> 1;
        const float* in = inp ? hr : pred;
        __half* mag = magBase + ((size_t)b * 2 + inp) * MAGSZ;
        p1_unit(in, mag, b, bx, zc, tid);
    }

    cg::this_grid().sync();

    // Phase 2: 1440 units = 120 bx * 6 zc * 2 b
    float acc = 0.f;
    for (int u = blockIdx.x; u < 1440; u += NB) {
        const int bx = u % 120;
        int r = u / 120;
        const int zc = r % 6;
        const int b  = r / 6;
        const __half* mP = magBase + ((size_t)b * 2 + 0) * MAGSZ;
        const __half* mH = magBase + ((size_t)b * 2 + 1) * MAGSZ;
        p2_unit(mP, mH, bx, zc, tid, acc);
    }

    tail_reduce(acc, partial, blockIdx.x, counter, NB, out, tid);
}

// ===================== fallback: R7 multi-dispatch chain =====================
__global__ __launch_bounds__(BDIM) void sobel_mag_v9(
    const float* __restrict__ pred, const float* __restrict__ hr,
    __half* __restrict__ magP, __half* __restrict__ magH,
    int b, unsigned* __restrict__ counter, int zeroCtr)
{
    if (zeroCtr && blockIdx.x == 0 && blockIdx.y == 0 && blockIdx.z == 0 &&
        threadIdx.x == 0)
        __hip_atomic_store(counter, 0u, __ATOMIC_RELAXED,
                           __HIP_MEMORY_SCOPE_AGENT);
    const float* in = blockIdx.z ? hr : pred;
    __half* mag = blockIdx.z ? magH : magP;
    p1_unit(in, mag, b, blockIdx.x, blockIdx.y, threadIdx.x);
}

__global__ __launch_bounds__(BDIM) void sobel2_v9(
    const __half* __restrict__ magP, const __half* __restrict__ magH,
    int b, float* __restrict__ partial, unsigned* __restrict__ counter,
    float* __restrict__ out)
{
    float acc = 0.f;
    p2_unit(magP, magH, blockIdx.x, blockIdx.y, threadIdx.x, acc);
    const size_t pidx = (size_t)b * 720 + (size_t)blockIdx.y * 120 + blockIdx.x;
    tail_reduce(acc, partial, pidx, counter, 1440u, out, (int)threadIdx.x);
}

extern "C" void kernel_launch(void* const* d_in, const int* in_sizes, int n_in,
                              void* d_out, int out_size, void* d_ws, size_t ws_size,
                              hipStream_t stream)
{
    const float* pred = (const float*)d_in[0];
    const float* hr   = (const float*)d_in[1];
    float* outp       = (float*)d_out;

    // ws layout: [0, 8KB): partials (512 fused / 1440 fallback)
    //            [32KB): unsigned last-block counter
    //            [64KB, ...): fp16 mag buffers (4 fused ~58MB / 2 fallback ~29MB)
    float* partial    = (float*)d_ws;
    unsigned* counter = (unsigned*)((char*)d_ws + 32768);
    __half* magBase   = (__half*)((char*)d_ws + 65536);

    const size_t need4 = 65536 + 4 * MAGSZ * sizeof(__half);

    bool done = false;
    if (ws_size >= need4) {
        void* args[] = { (void*)&pred, (void*)&hr, (void*)&magBase,
                         (void*)&partial, (void*)&counter, (void*)&outp };
        done = hipLaunchCooperativeKernel((const void*)sobel_fused,
                                          dim3(NB), dim3(BDIM), args, 0,
                                          stream) == hipSuccess;
    }
    if (!done) {
        __half* magP = magBase;
        __half* magH = magBase + MAGSZ;
        for (int b = 0; b < 2; ++b) {
            sobel_mag_v9<<<dim3(62, 8, 2), BDIM, 0, stream>>>(
                pred, hr, magP, magH, b, counter, b == 0 ? 1 : 0);
            sobel2_v9<<<dim3(120, 6), BDIM, 0, stream>>>(
                magP, magH, b, partial, counter, outp);
        }
    }
}

// Round 6
// 268.108 us; speedup vs baseline: 1.1957x; 1.1957x over previous
//
#include <hip/hip_runtime.h>
#include <hip/hip_fp16.h>

// Problem geometry: inputs (B=2, D=64, H=64, W=64, C=32) fp32, C innermost.
// Pass1: Sobel (VALID) -> mag = sqrt(gx^2+gy^2+gz^2) at 62^3 per (b,c)
// Pass2: Sobel on mag -> out = sqrt(gx^2+gy^2) + gz^2 at 60^3
// Result: mean(|out_pred - out_hr|) over 2*32*60^3 = 13,824,000 elems.
//
// R10: P2 wide-load remap. Evidence: wall-vs-kernel gap is harness-fixed
// (R9: 1 dispatch, gap grew) -> optimize kernel sum. R7 best: P1 44us @
// 2.1 TB/s (near the ~9 GB/s/CU per-CU miss-BW ceiling observed across all
// structures), P2 44.8us @ 0.84 TB/s (request-starved: 4B loads, 256B/wave).
// Fix P2 only: 4 channels/thread -> 8B half4 loads, 512B/wave-load, 12KB
// requested per wave-step (P1's proven shape). z-chunk 5, grid (60,12)=720.
// P1 + launch structure + fused finalize: verbatim R7 (proven fastest).

constexpr int BDIM = 256;
constexpr size_t IN_B = 8388608;   // floats per batch
constexpr int IN_D = 131072;       // floats per z-plane
constexpr int IN_H = 2048;         // floats per y-row
constexpr int M = 62;              // mag spatial dim
constexpr int F = 60;              // final spatial dim
constexpr int C = 32;
constexpr int MROW = M * C;                      // 1984 halves per mag row
constexpr size_t MAGSZ = (size_t)M * M * MROW;   // halves per mag buffer
constexpr size_t PLANE = (size_t)M * MROW;       // halves per mag z-plane
constexpr unsigned NPART = 1440;                 // 720 blocks x 2 batches

__device__ __forceinline__ float4 ld4(const float* p) {
    return *reinterpret_cast<const float4*>(p);
}
// 8B load of 4 consecutive fp16 channels -> float4
__device__ __forceinline__ float4 ldh4(const __half* p) {
    float2 r = *reinterpret_cast<const float2*>(p);
    const __half2* h = reinterpret_cast<const __half2*>(&r);
    float2 lo = __half22float2(h[0]), hi = __half22float2(h[1]);
    return make_float4(lo.x, lo.y, hi.x, hi.y);
}
__device__ __forceinline__ float4 sm3(float4 a, float4 b, float4 c) {
    return make_float4(a.x + 2.f * b.x + c.x, a.y + 2.f * b.y + c.y,
                       a.z + 2.f * b.z + c.z, a.w + 2.f * b.w + c.w);
}
__device__ __forceinline__ float4 df2(float4 a, float4 c) {
    return make_float4(c.x - a.x, c.y - a.y, c.z - a.z, c.w - a.w);
}

// ===================== Pass 1 (R7 body, verbatim, proven) =====================
struct P1W { float4 A[2], B[2], C[2]; };

__device__ __forceinline__ void p1_plane(const float* __restrict__ col, size_t zoff,
                                         P1W& W)
{
    float4 S[4], D[4];
#pragma unroll
    for (int r = 0; r < 4; ++r) {
        const float* p = col + zoff + (size_t)r * IN_H;
        float4 a = ld4(p), b = ld4(p + C), c = ld4(p + 2 * C);
        S[r] = sm3(a, b, c);
        D[r] = df2(a, c);
    }
#pragma unroll
    for (int k = 0; k < 2; ++k) {
        W.A[k] = sm3(S[k], S[k+1], S[k+2]);
        W.B[k] = df2(S[k], S[k+2]);
        W.C[k] = sm3(D[k], D[k+1], D[k+2]);
    }
}

__device__ __forceinline__ void p1_emit(const P1W& W0, const P1W& W1, const P1W& W2,
                                        __half* __restrict__ mag, size_t cb,
                                        int z, int y0, bool wr)
{
    if (!wr) return;
#pragma unroll
    for (int k = 0; k < 2; ++k) {
        float4 gx = df2(W0.A[k], W2.A[k]);
        float4 gy = sm3(W0.B[k], W1.B[k], W2.B[k]);
        float4 gz = sm3(W0.C[k], W1.C[k], W2.C[k]);
        float m0 = sqrtf(gx.x * gx.x + gy.x * gy.x + gz.x * gz.x);
        float m1 = sqrtf(gx.y * gx.y + gy.y * gy.y + gz.y * gz.y);
        float m2 = sqrtf(gx.z * gx.z + gy.z * gy.z + gz.z * gz.z);
        float m3 = sqrtf(gx.w * gx.w + gy.w * gy.w + gz.w * gz.w);
        union { __half2 h[2]; float2 f; } u;
        u.h[0] = __floats2half2_rn(m0, m1);
        u.h[1] = __floats2half2_rn(m2, m3);
        *reinterpret_cast<float2*>(mag + ((size_t)z * M + (y0 + k)) * MROW + cb)
            = u.f;
    }
}

__device__ __forceinline__ void p1_unit(const float* __restrict__ in,
                                        __half* __restrict__ mag,
                                        int b, int bx, int zc, int tid)
{
    const int xt = bx & 1, yt = bx >> 1;
    const int c4 = (tid & 7) << 2;           // channel base 0..28
    const int xl = tid >> 3;                 // 0..31
    const int x  = xt * 30 + xl;             // output x in [0,62)
    const bool wr = (xt == 0) || (xl >= 2);  // tile1 skips duplicated x=30,31
    const int y0 = yt * 2;
    const int z0 = zc * 8;
    const int zn = min(8, M - z0);           // 8, last chunk 6

    const float* col = in + (size_t)b * IN_B + (size_t)y0 * IN_H
                          + (size_t)x * C + c4;
    const size_t cb = (size_t)x * C + c4;

    P1W W0, W1, W2;
    p1_plane(col, (size_t)(z0 + 0) * IN_D, W0);
    p1_plane(col, (size_t)(z0 + 1) * IN_D, W1);
    int z = 0;
    while (true) {
        p1_plane(col, (size_t)(z0 + z + 2) * IN_D, W2);
        p1_emit(W0, W1, W2, mag, cb, z0 + z, y0, wr);
        if (++z >= zn) break;
        p1_plane(col, (size_t)(z0 + z + 2) * IN_D, W0);
        p1_emit(W1, W2, W0, mag, cb, z0 + z, y0, wr);
        if (++z >= zn) break;
        p1_plane(col, (size_t)(z0 + z + 2) * IN_D, W1);
        p1_emit(W2, W0, W1, mag, cb, z0 + z, y0, wr);
        if (++z >= zn) break;
    }
}

__global__ __launch_bounds__(BDIM) void sobel_mag_v10(
    const float* __restrict__ pred, const float* __restrict__ hr,
    __half* __restrict__ magP, __half* __restrict__ magH,
    int b, unsigned* __restrict__ counter, int zeroCtr)
{
    if (zeroCtr && blockIdx.x == 0 && blockIdx.y == 0 && blockIdx.z == 0 &&
        threadIdx.x == 0)
        __hip_atomic_store(counter, 0u, __ATOMIC_RELAXED,
                           __HIP_MEMORY_SCOPE_AGENT);
    const float* in = blockIdx.z ? hr : pred;
    __half* mag = blockIdx.z ? magH : magP;
    p1_unit(in, mag, b, blockIdx.x, blockIdx.y, threadIdx.x);
}

// ============ Pass 2 v10: 4 channels/thread, 8B loads, z-chunk 5 ============
struct P2W4 { float4 A[2], B[2], C[2]; };

__device__ __forceinline__ void p2_plane4(const __half* __restrict__ col,
                                          size_t zoff, P2W4& W)
{
    float4 S[4], D[4];
#pragma unroll
    for (int r = 0; r < 4; ++r) {
        const __half* p = col + zoff + (size_t)r * MROW;
        float4 a = ldh4(p), b = ldh4(p + C), c = ldh4(p + 2 * C);
        S[r] = sm3(a, b, c);          // x-smooth
        D[r] = df2(a, c);             // x-diff
    }
#pragma unroll
    for (int k = 0; k < 2; ++k) {
        W.A[k] = sm3(S[k], S[k+1], S[k+2]);   // y-smooth(x-smooth)
        W.B[k] = df2(S[k], S[k+2]);           // y-diff(x-smooth)
        W.C[k] = sm3(D[k], D[k+1], D[k+2]);   // y-smooth(x-diff)
    }
}

__device__ __forceinline__ void p2_emit4(const P2W4& P0, const P2W4& P1, const P2W4& P2,
                                         const P2W4& H0, const P2W4& H1, const P2W4& H2,
                                         float& acc)
{
#pragma unroll
    for (int k = 0; k < 2; ++k) {
        float4 gxP = df2(P0.A[k], P2.A[k]);            // d0-deriv
        float4 gyP = sm3(P0.B[k], P1.B[k], P2.B[k]);   // d1-deriv
        float4 gzP = sm3(P0.C[k], P1.C[k], P2.C[k]);   // d2-deriv
        float4 gxH = df2(H0.A[k], H2.A[k]);
        float4 gyH = sm3(H0.B[k], H1.B[k], H2.B[k]);
        float4 gzH = sm3(H0.C[k], H1.C[k], H2.C[k]);
        acc += fabsf((sqrtf(gxP.x*gxP.x + gyP.x*gyP.x) + gzP.x*gzP.x)
                   - (sqrtf(gxH.x*gxH.x + gyH.x*gyH.x) + gzH.x*gzH.x));
        acc += fabsf((sqrtf(gxP.y*gxP.y + gyP.y*gyP.y) + gzP.y*gzP.y)
                   - (sqrtf(gxH.y*gxH.y + gyH.y*gyH.y) + gzH.y*gzH.y));
        acc += fabsf((sqrtf(gxP.z*gxP.z + gyP.z*gyP.z) + gzP.z*gzP.z)
                   - (sqrtf(gxH.z*gxH.z + gyH.z*gyH.z) + gzH.z*gzH.z));
        acc += fabsf((sqrtf(gxP.w*gxP.w + gyP.w*gyP.w) + gzP.w*gzP.w)
                   - (sqrtf(gxH.w*gxH.w + gyH.w*gyH.w) + gzH.w*gzH.w));
    }
}

// grid (60, 12): bx -> xt = bx&1 (2 x-tiles of 30), yt = bx>>1 (30 y-tiles of 2).
// zc in [0,12): 5 output z per chunk; planes z0..z0+6 (max 61, in bounds).
__global__ __launch_bounds__(BDIM) void sobel2_v10(
    const __half* __restrict__ magP, const __half* __restrict__ magH,
    int b, float* __restrict__ partial, unsigned* __restrict__ counter,
    float* __restrict__ out)
{
    const int bx = blockIdx.x;
    const int xt = bx & 1, yt = bx >> 1;   // yt 0..29
    const int zc = blockIdx.y;             // 0..11
    const int y0 = yt * 2;
    const int z0 = zc * 5;
    const int tid = threadIdx.x;
    const int c4 = (tid & 7) << 2;         // channel base 0..28
    const int xl = tid >> 3;               // 0..31
    const bool wr = xl < 30;               // 30 outputs per x-tile
    const int xo = xt * 30 + min(xl, 29);  // output x (idle threads clamped)

    const size_t colo = (size_t)y0 * MROW + (size_t)xo * C + c4;
    const __half* colP = magP + colo;
    const __half* colH = magH + colo;

    P2W4 P0, P1, P2, H0, H1, H2;
    float acc = 0.f;
    p2_plane4(colP, (size_t)(z0 + 0) * PLANE, P0);
    p2_plane4(colH, (size_t)(z0 + 0) * PLANE, H0);
    p2_plane4(colP, (size_t)(z0 + 1) * PLANE, P1);
    p2_plane4(colH, (size_t)(z0 + 1) * PLANE, H1);

    p2_plane4(colP, (size_t)(z0 + 2) * PLANE, P2);
    p2_plane4(colH, (size_t)(z0 + 2) * PLANE, H2);
    if (wr) p2_emit4(P0, P1, P2, H0, H1, H2, acc);
    p2_plane4(colP, (size_t)(z0 + 3) * PLANE, P0);
    p2_plane4(colH, (size_t)(z0 + 3) * PLANE, H0);
    if (wr) p2_emit4(P1, P2, P0, H1, H2, H0, acc);
    p2_plane4(colP, (size_t)(z0 + 4) * PLANE, P1);
    p2_plane4(colH, (size_t)(z0 + 4) * PLANE, H1);
    if (wr) p2_emit4(P2, P0, P1, H2, H0, H1, acc);
    p2_plane4(colP, (size_t)(z0 + 5) * PLANE, P2);
    p2_plane4(colH, (size_t)(z0 + 5) * PLANE, H2);
    if (wr) p2_emit4(P0, P1, P2, H0, H1, H2, acc);
    p2_plane4(colP, (size_t)(z0 + 6) * PLANE, P0);
    p2_plane4(colH, (size_t)(z0 + 6) * PLANE, H0);
    if (wr) p2_emit4(P1, P2, P0, H1, H2, H0, acc);

    // block reduction + globally-last-block finalize
    for (int o = 32; o > 0; o >>= 1) acc += __shfl_down(acc, o, 64);
    __shared__ float sred[BDIM / 64];
    __shared__ int isLast;
    __shared__ double sd[BDIM / 64];
    const int lane = tid & 63, wv = tid >> 6;
    if (lane == 0) sred[wv] = acc;
    __syncthreads();
    if (tid == 0) {
        float t = 0.f;
#pragma unroll
        for (int i = 0; i < BDIM / 64; ++i) t += sred[i];
        const size_t pidx = (size_t)b * 720 + (size_t)zc * 60 + bx;
        __hip_atomic_store(&partial[pidx], t, __ATOMIC_RELAXED,
                           __HIP_MEMORY_SCOPE_AGENT);
        const unsigned old = __hip_atomic_fetch_add(counter, 1u, __ATOMIC_ACQ_REL,
                                                    __HIP_MEMORY_SCOPE_AGENT);
        isLast = (old == NPART - 1u) ? 1 : 0;
    }
    __syncthreads();
    if (isLast) {
        double a = 0.0;
        for (unsigned i = tid; i < NPART; i += BDIM)
            a += (double)__hip_atomic_load(&partial[i], __ATOMIC_RELAXED,
                                           __HIP_MEMORY_SCOPE_AGENT);
        for (int o = 32; o > 0; o >>= 1) a += __shfl_down(a, o, 64);
        if (lane == 0) sd[wv] = a;
        __syncthreads();
        if (tid == 0) {
            double t = 0.0;
#pragma unroll
            for (int i = 0; i < BDIM / 64; ++i) t += sd[i];
            out[0] = (float)(t / 13824000.0);
        }
    }
}

extern "C" void kernel_launch(void* const* d_in, const int* in_sizes, int n_in,
                              void* d_out, int out_size, void* d_ws, size_t ws_size,
                              hipStream_t stream)
{
    const float* pred = (const float*)d_in[0];
    const float* hr   = (const float*)d_in[1];

    // ws layout: [0, 5.76KB): 1440 float partials
    //            [32KB): unsigned last-block counter (zeroed by P1(b0))
    //            [64KB, ...): 2 fp16 mag buffers (~29.2 MB), reused per batch
    float* partial    = (float*)d_ws;
    unsigned* counter = (unsigned*)((char*)d_ws + 32768);
    __half* magP = (__half*)((char*)d_ws + 65536);
    __half* magH = magP + MAGSZ;

    for (int b = 0; b < 2; ++b) {
        sobel_mag_v10<<<dim3(62, 8, 2), BDIM, 0, stream>>>(
            pred, hr, magP, magH, b, counter, b == 0 ? 1 : 0);
        sobel2_v10<<<dim3(60, 12), BDIM, 0, stream>>>(
            magP, magH, b, partial, counter, (float*)d_out);
    }
}